// Round 9
// baseline (207.204 us; speedup 1.0000x reference)
//
#include <hip/hip_runtime.h>
#include <math.h>

#define BSZ    4
#define NTOK   6400      // 40*160
#define DMODEL 256
#define NHEAD  8
#define HDIM   32
#define NPTS   9
#define HSP    40
#define WSP    160
#define KDIM   256
#define MTOT   (BSZ*NTOK)   // 25600

typedef short  short8  __attribute__((ext_vector_type(8)));
typedef float  floatx4 __attribute__((ext_vector_type(4)));
typedef float  f32x2   __attribute__((ext_vector_type(2)));

__device__ __forceinline__ ushort f2bf(float f) {
    uint u = __float_as_uint(f);
    u = (u + 0x7FFFu + ((u >> 16) & 1u)) >> 16;   // RNE
    return (ushort)u;
}

// unpack 8 packed bf16 (uint4) -> 4 x f32x2 (pairs, channel order preserved)
__device__ __forceinline__ void unpack8v(uint4 u, f32x2* f) {
    f[0].x = __uint_as_float(u.x << 16); f[0].y = __uint_as_float(u.x & 0xFFFF0000u);
    f[1].x = __uint_as_float(u.y << 16); f[1].y = __uint_as_float(u.y & 0xFFFF0000u);
    f[2].x = __uint_as_float(u.z << 16); f[2].y = __uint_as_float(u.z & 0xFFFF0000u);
    f[3].x = __uint_as_float(u.w << 16); f[3].y = __uint_as_float(u.w & 0xFFFF0000u);
}

// dot of 8 bf16 (packed in uint4) with q2[4] (f32x2 pairs) -> scalar
__device__ __forceinline__ float dot8(uint4 u, const f32x2* q2) {
    f32x2 a; a.x = 0.f; a.y = 0.f;
    f32x2 t;
    t.x = __uint_as_float(u.x << 16); t.y = __uint_as_float(u.x & 0xFFFF0000u);
    a += t * q2[0];
    t.x = __uint_as_float(u.y << 16); t.y = __uint_as_float(u.y & 0xFFFF0000u);
    a += t * q2[1];
    t.x = __uint_as_float(u.z << 16); t.y = __uint_as_float(u.z & 0xFFFF0000u);
    a += t * q2[2];
    t.x = __uint_as_float(u.w << 16); t.y = __uint_as_float(u.w & 0xFFFF0000u);
    a += t * q2[3];
    return a.x + a.y;
}

#define AS1C(p) ((const __attribute__((address_space(1))) void*)(p))
#define AS3(p)  ((__attribute__((address_space(3))) void*)(p))

// ---------------------------------------------------------------------------
// All fp32->bf16 casts (r7 config: xb path is cheaper than fp32-direct A,
// proven by r8 regression).  1680 blocks x 4096 elems, 4 independent float4
// chains per thread.  X-region XCD-affinity-swizzled (panel p -> XCD p/50,
// matching gemm's reader map).
// Logical regions (4096-elem blocks o): x[0,1600) wq[1600,1616)
//   woff[1616,1625) pad[1625,1632) wkv[1632,1664) wout[1664,1680)
// wf layout (1024x256 bf16): rows[0,256)=Wq [256,400)=Woff [400,512)=0
//   [512,1024)=Wkv
// ---------------------------------------------------------------------------
__global__ __launch_bounds__(256) void cast_all(
    const float* __restrict__ x,   const float* __restrict__ Wq,
    const float* __restrict__ Woff,const float* __restrict__ Wkv,
    const float* __restrict__ Wout,
    ushort* __restrict__ xb, ushort* __restrict__ wf, ushort* __restrict__ woutb)
{
    const int bid = blockIdx.x;
    const int o = (bid < 1600) ? ((bid >> 3) + (bid & 7) * 200) : bid;
    if (o >= 1625 && o < 1632) {   // zero-fill wf rows 400..511
        const int i = (o - 1625) * 4096 + threadIdx.x * 4;
        ushort4 z; z.x = 0; z.y = 0; z.z = 0; z.w = 0;
        #pragma unroll
        for (int k = 0; k < 4; ++k)
            *(ushort4*)(wf + 400 * 256 + i + k * 1024) = z;
        return;
    }
    const float* src; ushort* dst; int base;
    if      (o < 1600) { src = x;    dst = xb;              base = o; }
    else if (o < 1616) { src = Wq;   dst = wf;              base = o - 1600; }
    else if (o < 1625) { src = Woff; dst = wf + 256 * 256;  base = o - 1616; }
    else if (o < 1664) { src = Wkv;  dst = wf + 512 * 256;  base = o - 1632; }
    else               { src = Wout; dst = woutb;           base = o - 1664; }
    const int i0 = base * 4096 + threadIdx.x * 4;
    float4 v[4];
    #pragma unroll
    for (int k = 0; k < 4; ++k) v[k] = *(const float4*)(src + i0 + k * 1024);
    #pragma unroll
    for (int k = 0; k < 4; ++k) {
        ushort4 o4;
        o4.x = f2bf(v[k].x); o4.y = f2bf(v[k].y);
        o4.z = f2bf(v[k].z); o4.w = f2bf(v[k].w);
        *(ushort4*)(dst + i0 + k * 1024) = o4;
    }
}

// ---------------------------------------------------------------------------
// 64x64-tile 2-phase double-buffered GEMM (r6/r7-proven TLP-first structure).
// N=1024 fused epilogue: q bf16 | off s16 fixed-point x4096 | k/v scatter.
// Offsets as s16 halves the off round-trip (29 -> 7 MB): tanh*4 in (-4,4),
// enc = rint(tanh*16384), decode mul 1/4096 (err 1.2e-4 px).
// XCD map: token-panel p on XCD p/50 (cross-kernel affinity, r7: FETCH -50%).
// ---------------------------------------------------------------------------
__global__ __launch_bounds__(256) void gemm_qokv(
    const ushort* __restrict__ Xb,
    const ushort* __restrict__ Wf,
    const float* __restrict__ bq, const float* __restrict__ boff,
    const float* __restrict__ bkv,
    ushort* __restrict__ qb, short* __restrict__ offp,
    ushort* __restrict__ kfb, ushort* __restrict__ vfb)
{
    constexpr int NBN = 16;                    // 64-col n-blocks per m-panel
    __shared__ ushort As[2][64 * 64];          // 2 x 8 KB
    __shared__ ushort Bs[2][64 * 64];          // 2 x 8 KB

    const int tid = threadIdx.x;
    const int bid = blockIdx.x;
    const int xcd = bid & 7;
    const int j   = bid >> 3;
    const int block_n = (j % NBN) * 64;
    const int block_m = (xcd * 50 + j / NBN) * 64;   // 400 m-panels, 50/XCD

    const int wave = tid >> 6, lane = tid & 63;
    const int wr = (wave >> 1) * 32, wc = (wave & 1) * 32;
    const int l15 = lane & 15, quad = lane >> 4;

    const int srow  = lane >> 3;                 // 0..7
    const int sslot = (lane & 7) ^ srow;         // pre-swizzled src slot

    floatx4 acc[2][2];
    #pragma unroll
    for (int i = 0; i < 2; ++i)
        #pragma unroll
        for (int jj = 0; jj < 2; ++jj) {
            acc[i][jj][0] = 0.f; acc[i][jj][1] = 0.f;
            acc[i][jj][2] = 0.f; acc[i][jj][3] = 0.f;
        }

    auto stage = [&](int buf, int kt) {
        #pragma unroll
        for (int i = 0; i < 2; ++i) {
            const int rb = wave * 16 + i * 8;
            const ushort* sa = Xb + (size_t)(block_m + rb + srow) * KDIM + kt + sslot * 8;
            const ushort* sb = Wf + (size_t)(block_n + rb + srow) * KDIM + kt + sslot * 8;
            __builtin_amdgcn_global_load_lds(AS1C(sa), AS3(&As[buf][rb * 64]), 16, 0, 0);
            __builtin_amdgcn_global_load_lds(AS1C(sb), AS3(&Bs[buf][rb * 64]), 16, 0, 0);
        }
    };

    auto compute = [&](int buf) {
        #pragma unroll
        for (int ks2 = 0; ks2 < 2; ++ks2) {
            short8 af[2], bfr[2];
            #pragma unroll
            for (int f = 0; f < 2; ++f) {
                const int ra  = wr + f * 16 + l15;
                const int rbb = wc + f * 16 + l15;
                const int sl  = (((ks2 * 4 + quad) ^ (l15 & 7))) * 8;
                af[f]  = *(const short8*)&As[buf][ra * 64 + sl];
                bfr[f] = *(const short8*)&Bs[buf][rbb * 64 + sl];
            }
            #pragma unroll
            for (int fm = 0; fm < 2; ++fm)
                #pragma unroll
                for (int fn = 0; fn < 2; ++fn)
                    acc[fm][fn] = __builtin_amdgcn_mfma_f32_16x16x32_bf16(
                        af[fm], bfr[fn], acc[fm][fn], 0, 0, 0);
        }
    };

    stage(0, 0);
    __syncthreads();
    #pragma unroll
    for (int t = 0; t < 3; ++t) {
        stage((t + 1) & 1, (t + 1) * 64);
        compute(t & 1);
        __syncthreads();
    }
    compute(1);   // tile 3 in buf 1

    // ---- epilogue: C/D layout col=lane&15, row=quad*4+reg ----
    const int bb  = block_m / NTOK;
    const int nn0 = block_m - bb * NTOK;
    #pragma unroll
    for (int fn = 0; fn < 2; ++fn) {
        const int col = block_n + wc + fn * 16 + l15;
        float bcol;
        if      (col < 256) bcol = bq[col];
        else if (col < 400) bcol = boff[col - 256];
        else if (col < 512) bcol = 0.f;
        else                bcol = bkv[col - 512];
        #pragma unroll
        for (int fm = 0; fm < 2; ++fm) {
            #pragma unroll
            for (int r = 0; r < 4; ++r) {
                const int rloc = wr + fm * 16 + quad * 4 + r;
                const int row  = block_m + rloc;
                const float val = acc[fm][fn][r] + bcol;
                if (col < 256) {
                    qb[(size_t)row * DMODEL + col] = f2bf(val);
                } else if (col < 400) {
                    offp[(size_t)row * 144 + (col - 256)] =
                        (short)__float2int_rn(tanhf(val) * 16384.0f);
                } else if (col >= 512) {
                    const int c2 = col - 512;
                    const int hh = (c2 & 255) >> 5, cc = c2 & 31;
                    const int nn = nn0 + rloc;
                    const size_t o = (((size_t)(bb * NHEAD + hh)) * NTOK + nn) * HDIM + cc;
                    if (c2 < 256) kfb[o] = f2bf(val);
                    else          vfb[o] = f2bf(val);
                }
            }
        }
    }
}

// ---------------------------------------------------------------------------
// FUSED deformable attention + out-projection.  Block = 16 tokens.
// Phase 1 (x2 iterations): flat sampling/attention (r8 structure) for
//   8 tokens x 8 heads per iteration; normalized bf16 results written to an
//   8 KB LDS tile A16[16][32 slots of 16B], slot XOR-swizzled (^ row&7).
// Phase 2: one barrier, then 16x256x256 MFMA tail: A from LDS (swizzled
//   ds_read_b128, conflict-free), B = Wout bf16 straight from L2 (128 KB,
//   chip-hot), fp32 d_out written directly.  attnb round-trip eliminated
//   (-26 MB) and one launch removed.
// XCD-affinity remap: block o covers tokens [o*16,(o+1)*16) = panel o/4,
// runs on XCD o/200 — matches gemm_qokv's writer map (r7-proven mechanism).
// Offsets decoded from s16 fixed-point (x4096).
// ---------------------------------------------------------------------------
__global__ __launch_bounds__(256) void deform_attn_out(
    const ushort* __restrict__ qb,    // (M,256) bf16
    const short* __restrict__ offp,   // (M,144) s16 x4096
    const ushort* __restrict__ kfb,   // (B*H,N,32) bf16
    const ushort* __restrict__ vfb,
    const ushort* __restrict__ woutb, // (256,256) bf16 row=out-col, k contig
    const float* __restrict__ bout,
    float* __restrict__ out)          // (M,256) fp32
{
    __shared__ ushort A16[16 * 256];  // 8 KB: [token][32 slots x 8 ushorts]

    const int tid  = threadIdx.x;
    const int wave = tid >> 6, lane = tid & 63;
    // affinity remap (bijective on [0,1600))
    const int o    = ((int)blockIdx.x >> 3) + ((int)blockIdx.x & 7) * 200;
    const int tok0 = o * 16;

    const int h  = (lane >> 2) & 7, lc = lane & 3;

    // ================= phase 1: sampling + attention =================
    #pragma unroll
    for (int it = 0; it < 2; ++it) {
        const int tloc  = it * 8 + wave * 2 + (lane >> 5);
        const int token = tok0 + tloc;
        const int b = token / NTOK, n = token % NTOK;

        const uint4 qu = *(const uint4*)(qb + (size_t)token * DMODEL + h * HDIM + lc * 8);
        f32x2 q2[4]; unpack8v(qu, q2);
        #pragma unroll
        for (int i = 0; i < 4; ++i) q2[i] *= 0.17677669529663687f;   // 32^-0.5

        const short* ob = offp + (size_t)token * 144 + h * (NPTS * 2);
        const float bx = (float)(n % WSP), by = (float)(n / WSP);
        const ushort* kbase = kfb + (size_t)(b * NHEAD + h) * NTOK * HDIM + lc * 8;
        const ushort* vbase = vfb + (size_t)(b * NHEAD + h) * NTOK * HDIM + lc * 8;

        // ---- setup: all 9 points (s16 decode) ----
        int   idx[NPTS][4];
        float wt[NPTS][4];
        #pragma unroll
        for (int p = 0; p < NPTS; ++p) {
            const int u = *(const int*)(ob + 2 * p);
            const float ofx = (float)((short)(u & 0xFFFF)) * (1.0f / 4096.0f);
            const float ofy = (float)(u >> 16) * (1.0f / 4096.0f);
            const float sx = bx + ofx, sy = by + ofy;
            const float fx0 = floorf(sx), fy0 = floorf(sy);
            const float wx1 = sx - fx0, wx0 = 1.0f - wx1;
            const float wy1 = sy - fy0, wy0 = 1.0f - wy1;
            const int ix0 = (int)fx0, iy0 = (int)fy0;
            const int ix1 = ix0 + 1, iy1 = iy0 + 1;
            const bool vx0 = (ix0 >= 0) & (ix0 <= WSP - 1);
            const bool vx1 = (ix1 >= 0) & (ix1 <= WSP - 1);
            const bool vy0 = (iy0 >= 0) & (iy0 <= HSP - 1);
            const bool vy1 = (iy1 >= 0) & (iy1 <= HSP - 1);
            const int cx0 = min(max(ix0, 0), WSP - 1);
            const int cx1 = min(max(ix1, 0), WSP - 1);
            const int cy0 = min(max(iy0, 0), HSP - 1);
            const int cy1 = min(max(iy1, 0), HSP - 1);
            wt[p][0] = wx0 * wy0 * (float)(vx0 && vy0);
            wt[p][1] = wx1 * wy0 * (float)(vx1 && vy0);
            wt[p][2] = wx0 * wy1 * (float)(vx0 && vy1);
            wt[p][3] = wx1 * wy1 * (float)(vx1 && vy1);
            idx[p][0] = (cy0 * WSP + cx0) * HDIM;
            idx[p][1] = (cy0 * WSP + cx1) * HDIM;
            idx[p][2] = (cy1 * WSP + cx0) * HDIM;
            idx[p][3] = (cy1 * WSP + cx1) * HDIM;
        }

        // ---- flat K phase ----
        float l[NPTS];
        #pragma unroll
        for (int p = 0; p < NPTS; ++p) {
            const uint4 k0 = *(const uint4*)(kbase + idx[p][0]);
            const uint4 k1 = *(const uint4*)(kbase + idx[p][1]);
            const uint4 k2 = *(const uint4*)(kbase + idx[p][2]);
            const uint4 k3 = *(const uint4*)(kbase + idx[p][3]);
            float part = wt[p][0] * dot8(k0, q2) + wt[p][1] * dot8(k1, q2)
                       + wt[p][2] * dot8(k2, q2) + wt[p][3] * dot8(k3, q2);
            part += __shfl_xor(part, 1, 64);
            part += __shfl_xor(part, 2, 64);
            l[p] = part;
        }

        // ---- plain-exp softmax (r7-proven: logits data-bounded) ----
        float s = 0.f, e[NPTS];
        #pragma unroll
        for (int p = 0; p < NPTS; ++p) { e[p] = __expf(l[p]); s += e[p]; }

        // ---- flat V phase ----
        f32x2 o2[4];
        #pragma unroll
        for (int i = 0; i < 4; ++i) { o2[i].x = 0.f; o2[i].y = 0.f; }
        #pragma unroll
        for (int p = 0; p < NPTS; ++p) {
            #pragma unroll
            for (int c = 0; c < 4; ++c) {
                const uint4 vu = *(const uint4*)(vbase + idx[p][c]);
                f32x2 vv[4]; unpack8v(vu, vv);
                const float ew = e[p] * wt[p][c];
                #pragma unroll
                for (int i = 0; i < 4; ++i) o2[i] += vv[i] * ew;
            }
        }

        // ---- normalize -> bf16 -> swizzled LDS ----
        const float inv = 1.0f / s;
        uint4 ru;
        ru.x = (uint)f2bf(o2[0].x * inv) | ((uint)f2bf(o2[0].y * inv) << 16);
        ru.y = (uint)f2bf(o2[1].x * inv) | ((uint)f2bf(o2[1].y * inv) << 16);
        ru.z = (uint)f2bf(o2[2].x * inv) | ((uint)f2bf(o2[2].y * inv) << 16);
        ru.w = (uint)f2bf(o2[3].x * inv) | ((uint)f2bf(o2[3].y * inv) << 16);
        const int slot = (h * 4 + lc) ^ (tloc & 7);
        *(uint4*)&A16[tloc * 256 + slot * 8] = ru;
    }

    __syncthreads();

    // ================= phase 2: out-projection MFMA tail =================
    // out[t, j] = sum_k A16[t,k] * Wout[j,k] + bout[j]; wave owns cols
    // [wave*64, wave*64+64).  A row = l15 (token), k-slot swizzled read.
    const int l15 = lane & 15, quad = lane >> 4;

    short8 af[8];
    #pragma unroll
    for (int ks = 0; ks < 8; ++ks) {
        const int sl = ((ks * 4 + quad) ^ (l15 & 7)) * 8;
        af[ks] = *(const short8*)&A16[l15 * 256 + sl];
    }

    floatx4 oacc[4];
    #pragma unroll
    for (int fn = 0; fn < 4; ++fn) {
        oacc[fn][0] = 0.f; oacc[fn][1] = 0.f; oacc[fn][2] = 0.f; oacc[fn][3] = 0.f;
    }
    #pragma unroll
    for (int fn = 0; fn < 4; ++fn) {
        const int col = wave * 64 + fn * 16 + l15;
        #pragma unroll
        for (int ks = 0; ks < 8; ++ks) {
            const short8 bfr = *(const short8*)(woutb + (size_t)col * 256
                                                + ks * 32 + quad * 8);
            oacc[fn] = __builtin_amdgcn_mfma_f32_16x16x32_bf16(
                af[ks], bfr, oacc[fn], 0, 0, 0);
        }
    }

    #pragma unroll
    for (int fn = 0; fn < 4; ++fn) {
        const int col = wave * 64 + fn * 16 + l15;
        const float bc = bout[col];
        #pragma unroll
        for (int r = 0; r < 4; ++r) {
            const int t = quad * 4 + r;       // token row (C/D: row=quad*4+reg)
            out[(size_t)(tok0 + t) * DMODEL + col] = oacc[fn][r] + bc;
        }
    }
}

// ---------------------------------------------------------------------------
extern "C" void kernel_launch(void* const* d_in, const int* in_sizes, int n_in,
                              void* d_out, int out_size, void* d_ws, size_t ws_size,
                              hipStream_t stream) {
    const float* x    = (const float*)d_in[0];
    const float* Wq   = (const float*)d_in[1];
    const float* bq   = (const float*)d_in[2];
    const float* Woff = (const float*)d_in[3];
    const float* boff = (const float*)d_in[4];
    const float* Wkv  = (const float*)d_in[5];
    const float* bkv  = (const float*)d_in[6];
    const float* Wout = (const float*)d_in[7];
    const float* bout = (const float*)d_in[8];

    // workspace layout (~61 MB)
    ushort* xb    = (ushort*)d_ws;                         // 6,553,600 us
    ushort* qb    = xb + (size_t)MTOT * DMODEL;            // 6,553,600 us
    short*  offp  = (short*)(qb + (size_t)MTOT * DMODEL);  // 3,686,400 s16
    ushort* kfb   = (ushort*)(offp + (size_t)MTOT * 144);  // 6,553,600 us
    ushort* vfb   = kfb + (size_t)MTOT * DMODEL;           // 6,553,600 us
    ushort* wf    = vfb + (size_t)MTOT * DMODEL;           // 262,144 us (1024x256)
    ushort* woutb = wf + 262144;                           // 65,536 us

    cast_all<<<dim3(1680), dim3(256), 0, stream>>>(x, Wq, Woff, Wkv, Wout,
                                                   xb, wf, woutb);

    gemm_qokv<<<dim3(6400), dim3(256), 0, stream>>>(xb, wf, bq, boff, bkv,
                                                    qb, offp, kfb, vfb);

    deform_attn_out<<<dim3(1600), dim3(256), 0, stream>>>(qb, offp, kfb, vfb,
                                                          woutb, bout,
                                                          (float*)d_out);
}

// Round 11
// 188.916 us; speedup vs baseline: 1.0968x; 1.0968x over previous
//
#include <hip/hip_runtime.h>
#include <math.h>

#define BSZ    4
#define NTOK   6400      // 40*160
#define DMODEL 256
#define NHEAD  8
#define HDIM   32
#define NPTS   9
#define HSP    40
#define WSP    160
#define KDIM   256
#define MTOT   (BSZ*NTOK)   // 25600

typedef short  short8  __attribute__((ext_vector_type(8)));
typedef float  floatx4 __attribute__((ext_vector_type(4)));
typedef float  f32x2   __attribute__((ext_vector_type(2)));

__device__ __forceinline__ ushort f2bf(float f) {
    uint u = __float_as_uint(f);
    u = (u + 0x7FFFu + ((u >> 16) & 1u)) >> 16;   // RNE
    return (ushort)u;
}

// unpack 8 packed bf16 (uint4) -> 4 x f32x2 (pairs, channel order preserved)
__device__ __forceinline__ void unpack8v(uint4 u, f32x2* f) {
    f[0].x = __uint_as_float(u.x << 16); f[0].y = __uint_as_float(u.x & 0xFFFF0000u);
    f[1].x = __uint_as_float(u.y << 16); f[1].y = __uint_as_float(u.y & 0xFFFF0000u);
    f[2].x = __uint_as_float(u.z << 16); f[2].y = __uint_as_float(u.z & 0xFFFF0000u);
    f[3].x = __uint_as_float(u.w << 16); f[3].y = __uint_as_float(u.w & 0xFFFF0000u);
}

// dot of 8 bf16 (packed in uint4) with q2[4] (f32x2 pairs) -> scalar
__device__ __forceinline__ float dot8(uint4 u, const f32x2* q2) {
    f32x2 a; a.x = 0.f; a.y = 0.f;
    f32x2 t;
    t.x = __uint_as_float(u.x << 16); t.y = __uint_as_float(u.x & 0xFFFF0000u);
    a += t * q2[0];
    t.x = __uint_as_float(u.y << 16); t.y = __uint_as_float(u.y & 0xFFFF0000u);
    a += t * q2[1];
    t.x = __uint_as_float(u.z << 16); t.y = __uint_as_float(u.z & 0xFFFF0000u);
    a += t * q2[2];
    t.x = __uint_as_float(u.w << 16); t.y = __uint_as_float(u.w & 0xFFFF0000u);
    a += t * q2[3];
    return a.x + a.y;
}

#define AS1C(p) ((const __attribute__((address_space(1))) void*)(p))
#define AS3(p)  ((__attribute__((address_space(3))) void*)(p))

// ---------------------------------------------------------------------------
// All fp32->bf16 casts (r7-measured config).  1680 blocks x 4096 elems, 4
// independent float4 chains per thread.  X-region XCD-affinity-swizzled
// (panel p -> XCD p/50, matching gemm's reader map).
// Logical regions (4096-elem blocks o): x[0,1600) wq[1600,1616)
//   woff[1616,1625) pad[1625,1632) wkv[1632,1664) wout[1664,1680)
// wf layout (1024x256 bf16): rows[0,256)=Wq [256,400)=Woff [400,512)=0
//   [512,1024)=Wkv
// ---------------------------------------------------------------------------
__global__ __launch_bounds__(256) void cast_all(
    const float* __restrict__ x,   const float* __restrict__ Wq,
    const float* __restrict__ Woff,const float* __restrict__ Wkv,
    const float* __restrict__ Wout,
    ushort* __restrict__ xb, ushort* __restrict__ wf, ushort* __restrict__ woutb)
{
    const int bid = blockIdx.x;
    const int o = (bid < 1600) ? ((bid >> 3) + (bid & 7) * 200) : bid;
    if (o >= 1625 && o < 1632) {   // zero-fill wf rows 400..511
        const int i = (o - 1625) * 4096 + threadIdx.x * 4;
        ushort4 z; z.x = 0; z.y = 0; z.z = 0; z.w = 0;
        #pragma unroll
        for (int k = 0; k < 4; ++k)
            *(ushort4*)(wf + 400 * 256 + i + k * 1024) = z;
        return;
    }
    const float* src; ushort* dst; int base;
    if      (o < 1600) { src = x;    dst = xb;              base = o; }
    else if (o < 1616) { src = Wq;   dst = wf;              base = o - 1600; }
    else if (o < 1625) { src = Woff; dst = wf + 256 * 256;  base = o - 1616; }
    else if (o < 1664) { src = Wkv;  dst = wf + 512 * 256;  base = o - 1632; }
    else               { src = Wout; dst = woutb;           base = o - 1664; }
    const int i0 = base * 4096 + threadIdx.x * 4;
    float4 v[4];
    #pragma unroll
    for (int k = 0; k < 4; ++k) v[k] = *(const float4*)(src + i0 + k * 1024);
    #pragma unroll
    for (int k = 0; k < 4; ++k) {
        ushort4 o4;
        o4.x = f2bf(v[k].x); o4.y = f2bf(v[k].y);
        o4.z = f2bf(v[k].z); o4.w = f2bf(v[k].w);
        *(ushort4*)(dst + i0 + k * 1024) = o4;
    }
}

// ---------------------------------------------------------------------------
// 64x64-tile 2-phase double-buffered GEMM (r6/r7-measured TLP-first: 32 KB
// LDS -> 5 blocks/CU).  stage(t+1) BEFORE compute(t), ONE __syncthreads per
// K-step.  XOR swizzle; XCD map: token-panel p on XCD p/50.
// MODE 0: N=1024 fused epilogue q bf16 | off s16 x4096 | k/v scatter
//   (grid 6400).  s16 offsets: tanh*4 in (-4,4), enc = rint(tanh*16384),
//   decode *(1/4096); r9-verified (absmax improved to 1.1e-3).
// MODE 1: N=256 fp32 out-projection (grid 1600).
// ---------------------------------------------------------------------------
template <int MODE>
__global__ __launch_bounds__(256) void gemm64(
    const ushort* __restrict__ Xb,
    const ushort* __restrict__ Wf,
    const float* __restrict__ bq, const float* __restrict__ boff,
    const float* __restrict__ bkv,
    ushort* __restrict__ qb, short* __restrict__ offp,
    ushort* __restrict__ kfb, ushort* __restrict__ vfb,
    float* __restrict__ Yout)
{
    constexpr int NBN = (MODE == 0) ? 16 : 4;  // 64-col n-blocks per m-panel
    __shared__ ushort As[2][64 * 64];          // 2 x 8 KB
    __shared__ ushort Bs[2][64 * 64];          // 2 x 8 KB

    const int tid = threadIdx.x;
    const int bid = blockIdx.x;
    const int xcd = bid & 7;
    const int j   = bid >> 3;
    const int block_n = (j % NBN) * 64;
    const int block_m = (xcd * 50 + j / NBN) * 64;   // 400 m-panels, 50/XCD

    const int wave = tid >> 6, lane = tid & 63;
    const int wr = (wave >> 1) * 32, wc = (wave & 1) * 32;
    const int l15 = lane & 15, quad = lane >> 4;

    const int srow  = lane >> 3;                 // 0..7
    const int sslot = (lane & 7) ^ srow;         // pre-swizzled src slot

    floatx4 acc[2][2];
    #pragma unroll
    for (int i = 0; i < 2; ++i)
        #pragma unroll
        for (int jj = 0; jj < 2; ++jj) {
            acc[i][jj][0] = 0.f; acc[i][jj][1] = 0.f;
            acc[i][jj][2] = 0.f; acc[i][jj][3] = 0.f;
        }

    auto stage = [&](int buf, int kt) {
        #pragma unroll
        for (int i = 0; i < 2; ++i) {
            const int rb = wave * 16 + i * 8;
            const ushort* sa = Xb + (size_t)(block_m + rb + srow) * KDIM + kt + sslot * 8;
            const ushort* sb = Wf + (size_t)(block_n + rb + srow) * KDIM + kt + sslot * 8;
            __builtin_amdgcn_global_load_lds(AS1C(sa), AS3(&As[buf][rb * 64]), 16, 0, 0);
            __builtin_amdgcn_global_load_lds(AS1C(sb), AS3(&Bs[buf][rb * 64]), 16, 0, 0);
        }
    };

    auto compute = [&](int buf) {
        #pragma unroll
        for (int ks2 = 0; ks2 < 2; ++ks2) {
            short8 af[2], bfr[2];
            #pragma unroll
            for (int f = 0; f < 2; ++f) {
                const int ra  = wr + f * 16 + l15;
                const int rbb = wc + f * 16 + l15;
                const int sl  = (((ks2 * 4 + quad) ^ (l15 & 7))) * 8;
                af[f]  = *(const short8*)&As[buf][ra * 64 + sl];
                bfr[f] = *(const short8*)&Bs[buf][rbb * 64 + sl];
            }
            #pragma unroll
            for (int fm = 0; fm < 2; ++fm)
                #pragma unroll
                for (int fn = 0; fn < 2; ++fn)
                    acc[fm][fn] = __builtin_amdgcn_mfma_f32_16x16x32_bf16(
                        af[fm], bfr[fn], acc[fm][fn], 0, 0, 0);
        }
    };

    stage(0, 0);
    __syncthreads();
    #pragma unroll
    for (int t = 0; t < 3; ++t) {
        stage((t + 1) & 1, (t + 1) * 64);
        compute(t & 1);
        __syncthreads();
    }
    compute(1);   // tile 3 in buf 1

    // ---- epilogue: C/D layout col=lane&15, row=quad*4+reg ----
    const int bb  = block_m / NTOK;
    const int nn0 = block_m - bb * NTOK;
    #pragma unroll
    for (int fn = 0; fn < 2; ++fn) {
        const int col = block_n + wc + fn * 16 + l15;
        float bcol;
        if (MODE == 1) {
            bcol = bq[col];
        } else {
            if      (col < 256) bcol = bq[col];
            else if (col < 400) bcol = boff[col - 256];
            else if (col < 512) bcol = 0.f;
            else                bcol = bkv[col - 512];
        }
        #pragma unroll
        for (int fm = 0; fm < 2; ++fm) {
            #pragma unroll
            for (int r = 0; r < 4; ++r) {
                const int rloc = wr + fm * 16 + quad * 4 + r;
                const int row  = block_m + rloc;
                const float val = acc[fm][fn][r] + bcol;
                if (MODE == 1) {
                    Yout[(size_t)row * DMODEL + col] = val;
                } else {
                    if (col < 256) {
                        qb[(size_t)row * DMODEL + col] = f2bf(val);
                    } else if (col < 400) {
                        offp[(size_t)row * 144 + (col - 256)] =
                            (short)__float2int_rn(tanhf(val) * 16384.0f);
                    } else if (col >= 512) {
                        const int c2 = col - 512;
                        const int hh = (c2 & 255) >> 5, cc = c2 & 31;
                        const int nn = nn0 + rloc;
                        const size_t o = (((size_t)(bb * NHEAD + hh)) * NTOK + nn) * HDIM + cc;
                        if (c2 < 256) kfb[o] = f2bf(val);
                        else          vfb[o] = f2bf(val);
                    }
                }
            }
        }
    }
}

// ---------------------------------------------------------------------------
// Deformable sampling + softmax attention (r7-measured structure: grouped
// 3x3, K burst + V burst, plain-exp softmax, XCD-affinity remap).
// Only change vs r7: offsets decoded from s16 fixed-point x4096 (halves the
// off read traffic; r9-verified numerics).
// ---------------------------------------------------------------------------
__global__ __launch_bounds__(256, 3) void deform_attn(
    const ushort* __restrict__ qb,    // (M,256) bf16
    const short* __restrict__ offp,   // (M,144) s16 x4096
    const ushort* __restrict__ kfb,   // (B*H,N,32) bf16
    const ushort* __restrict__ vfb,
    ushort* __restrict__ attnb)       // (M,256) bf16
{
    const int lane = threadIdx.x & 63;
    // affinity remap: o = (bid>>3) + (bid&7)*400  (bijective on [0,3200))
    const int o = ((int)blockIdx.x >> 3) + ((int)blockIdx.x & 7) * 400;
    const int token = o * 8 + (threadIdx.x >> 6) * 2 + (lane >> 5);
    const int h = (lane >> 2) & 7, lc = lane & 3;
    const int b = token / NTOK, n = token % NTOK;

    const uint4 qu = *(const uint4*)(qb + (size_t)token * DMODEL + h * HDIM + lc * 8);
    f32x2 q2[4]; unpack8v(qu, q2);
    #pragma unroll
    for (int i = 0; i < 4; ++i) q2[i] *= 0.17677669529663687f;   // 32^-0.5

    const short* ob = offp + (size_t)token * 144 + h * (NPTS * 2);
    const float bx = (float)(n % WSP), by = (float)(n / WSP);
    const ushort* kbase = kfb + (size_t)(b * NHEAD + h) * NTOK * HDIM + lc * 8;
    const ushort* vbase = vfb + (size_t)(b * NHEAD + h) * NTOK * HDIM + lc * 8;

    float s = 0.f;
    f32x2 o2[4];
    #pragma unroll
    for (int i = 0; i < 4; ++i) { o2[i].x = 0.f; o2[i].y = 0.f; }

    #pragma unroll
    for (int g = 0; g < 3; ++g) {
        int   idx[3][4];
        float wt[3][4];
        #pragma unroll
        for (int jj = 0; jj < 3; ++jj) {
            const int p = g * 3 + jj;
            const int u = *(const int*)(ob + 2 * p);
            const float ofx = (float)((short)(u & 0xFFFF)) * (1.0f / 4096.0f);
            const float ofy = (float)(u >> 16) * (1.0f / 4096.0f);
            const float sx = bx + ofx, sy = by + ofy;
            const float fx0 = floorf(sx), fy0 = floorf(sy);
            const float wx1 = sx - fx0, wx0 = 1.0f - wx1;
            const float wy1 = sy - fy0, wy0 = 1.0f - wy1;
            const int ix0 = (int)fx0, iy0 = (int)fy0;
            const int ix1 = ix0 + 1, iy1 = iy0 + 1;
            const bool vx0 = (ix0 >= 0) & (ix0 <= WSP - 1);
            const bool vx1 = (ix1 >= 0) & (ix1 <= WSP - 1);
            const bool vy0 = (iy0 >= 0) & (iy0 <= HSP - 1);
            const bool vy1 = (iy1 >= 0) & (iy1 <= HSP - 1);
            const int cx0 = min(max(ix0, 0), WSP - 1);
            const int cx1 = min(max(ix1, 0), WSP - 1);
            const int cy0 = min(max(iy0, 0), HSP - 1);
            const int cy1 = min(max(iy1, 0), HSP - 1);
            wt[jj][0] = wx0 * wy0 * (float)(vx0 && vy0);
            wt[jj][1] = wx1 * wy0 * (float)(vx1 && vy0);
            wt[jj][2] = wx0 * wy1 * (float)(vx0 && vy1);
            wt[jj][3] = wx1 * wy1 * (float)(vx1 && vy1);
            idx[jj][0] = (cy0 * WSP + cx0) * HDIM;
            idx[jj][1] = (cy0 * WSP + cx1) * HDIM;
            idx[jj][2] = (cy1 * WSP + cx0) * HDIM;
            idx[jj][3] = (cy1 * WSP + cx1) * HDIM;
        }

        // --- K burst (12) then V burst (12): 24 loads in flight ---
        uint4 ku[12], vu[12];
        #pragma unroll
        for (int jj = 0; jj < 3; ++jj)
            #pragma unroll
            for (int c = 0; c < 4; ++c)
                ku[jj * 4 + c] = *(const uint4*)(kbase + idx[jj][c]);
        #pragma unroll
        for (int jj = 0; jj < 3; ++jj)
            #pragma unroll
            for (int c = 0; c < 4; ++c)
                vu[jj * 4 + c] = *(const uint4*)(vbase + idx[jj][c]);

        // --- dots (consume K while V still in flight) ---
        float l[3];
        #pragma unroll
        for (int jj = 0; jj < 3; ++jj) {
            float part = wt[jj][0] * dot8(ku[jj * 4 + 0], q2)
                       + wt[jj][1] * dot8(ku[jj * 4 + 1], q2)
                       + wt[jj][2] * dot8(ku[jj * 4 + 2], q2)
                       + wt[jj][3] * dot8(ku[jj * 4 + 3], q2);
            part += __shfl_xor(part, 1, 64);
            part += __shfl_xor(part, 2, 64);
            l[jj] = part;
        }

        // --- plain-exp softmax accumulation (r7-proven: logits bounded) ---
        const float e0 = __expf(l[0]);
        const float e1 = __expf(l[1]);
        const float e2 = __expf(l[2]);
        s += e0 + e1 + e2;
        const float e[3] = {e0, e1, e2};

        // --- V accumulate ---
        #pragma unroll
        for (int jj = 0; jj < 3; ++jj) {
            #pragma unroll
            for (int c = 0; c < 4; ++c) {
                f32x2 vv[4]; unpack8v(vu[jj * 4 + c], vv);
                const float ew = e[jj] * wt[jj][c];
                #pragma unroll
                for (int i = 0; i < 4; ++i) o2[i] += vv[i] * ew;
            }
        }
    }

    const float inv = 1.0f / s;
    uint4 ru;
    ru.x = (uint)f2bf(o2[0].x * inv) | ((uint)f2bf(o2[0].y * inv) << 16);
    ru.y = (uint)f2bf(o2[1].x * inv) | ((uint)f2bf(o2[1].y * inv) << 16);
    ru.z = (uint)f2bf(o2[2].x * inv) | ((uint)f2bf(o2[2].y * inv) << 16);
    ru.w = (uint)f2bf(o2[3].x * inv) | ((uint)f2bf(o2[3].y * inv) << 16);
    *(uint4*)(attnb + (size_t)token * DMODEL + h * HDIM + lc * 8) = ru;
}

// ---------------------------------------------------------------------------
extern "C" void kernel_launch(void* const* d_in, const int* in_sizes, int n_in,
                              void* d_out, int out_size, void* d_ws, size_t ws_size,
                              hipStream_t stream) {
    const float* x    = (const float*)d_in[0];
    const float* Wq   = (const float*)d_in[1];
    const float* bq   = (const float*)d_in[2];
    const float* Woff = (const float*)d_in[3];
    const float* boff = (const float*)d_in[4];
    const float* Wkv  = (const float*)d_in[5];
    const float* bkv  = (const float*)d_in[6];
    const float* Wout = (const float*)d_in[7];
    const float* bout = (const float*)d_in[8];

    // workspace layout (~61 MB)
    ushort* xb    = (ushort*)d_ws;                         // 6,553,600 us (aliased by attnb)
    ushort* qb    = xb + (size_t)MTOT * DMODEL;            // 6,553,600 us
    short*  offp  = (short*)(qb + (size_t)MTOT * DMODEL);  // 3,686,400 s16
    ushort* kfb   = (ushort*)(offp + (size_t)MTOT * 144);  // 6,553,600 us
    ushort* vfb   = kfb + (size_t)MTOT * DMODEL;           // 6,553,600 us
    ushort* wf    = vfb + (size_t)MTOT * DMODEL;           // 262,144 us (1024x256)
    ushort* woutb = wf + 262144;                           // 65,536 us
    ushort* attnb = xb;   // xb dead after gemm64<0>

    cast_all<<<dim3(1680), dim3(256), 0, stream>>>(x, Wq, Woff, Wkv, Wout,
                                                   xb, wf, woutb);

    gemm64<0><<<dim3(6400), dim3(256), 0, stream>>>(xb, wf, bq, boff, bkv,
                                                    qb, offp, kfb, vfb, nullptr);

    deform_attn<<<dim3(3200), dim3(256), 0, stream>>>(qb, offp, kfb, vfb, attnb);

    gemm64<1><<<dim3(1600), dim3(256), 0, stream>>>(attnb, woutb, bout,
                                                    nullptr, nullptr, nullptr,
                                                    nullptr, nullptr, nullptr,
                                                    (float*)d_out);
}

// Round 12
// 188.175 us; speedup vs baseline: 1.1011x; 1.0039x over previous
//
#include <hip/hip_runtime.h>
#include <math.h>

#define BSZ    4
#define NTOK   6400      // 40*160
#define DMODEL 256
#define NHEAD  8
#define HDIM   32
#define NPTS   9
#define HSP    40
#define WSP    160
#define KDIM   256
#define MTOT   (BSZ*NTOK)   // 25600

typedef short  short8  __attribute__((ext_vector_type(8)));
typedef float  floatx4 __attribute__((ext_vector_type(4)));
typedef float  f32x2   __attribute__((ext_vector_type(2)));

__device__ __forceinline__ ushort f2bf(float f) {
    uint u = __float_as_uint(f);
    u = (u + 0x7FFFu + ((u >> 16) & 1u)) >> 16;   // RNE
    return (ushort)u;
}

// unpack 8 packed bf16 (uint4) -> 4 x f32x2 (pairs, channel order preserved)
__device__ __forceinline__ void unpack8v(uint4 u, f32x2* f) {
    f[0].x = __uint_as_float(u.x << 16); f[0].y = __uint_as_float(u.x & 0xFFFF0000u);
    f[1].x = __uint_as_float(u.y << 16); f[1].y = __uint_as_float(u.y & 0xFFFF0000u);
    f[2].x = __uint_as_float(u.z << 16); f[2].y = __uint_as_float(u.z & 0xFFFF0000u);
    f[3].x = __uint_as_float(u.w << 16); f[3].y = __uint_as_float(u.w & 0xFFFF0000u);
}

// dot of 8 bf16 (packed in uint4) with q2[4] (f32x2 pairs) -> scalar
__device__ __forceinline__ float dot8(uint4 u, const f32x2* q2) {
    f32x2 a; a.x = 0.f; a.y = 0.f;
    f32x2 t;
    t.x = __uint_as_float(u.x << 16); t.y = __uint_as_float(u.x & 0xFFFF0000u);
    a += t * q2[0];
    t.x = __uint_as_float(u.y << 16); t.y = __uint_as_float(u.y & 0xFFFF0000u);
    a += t * q2[1];
    t.x = __uint_as_float(u.z << 16); t.y = __uint_as_float(u.z & 0xFFFF0000u);
    a += t * q2[2];
    t.x = __uint_as_float(u.w << 16); t.y = __uint_as_float(u.w & 0xFFFF0000u);
    a += t * q2[3];
    return a.x + a.y;
}

#define AS1C(p) ((const __attribute__((address_space(1))) void*)(p))
#define AS3(p)  ((__attribute__((address_space(3))) void*)(p))

// ---------------------------------------------------------------------------
// All fp32->bf16 casts (r7-measured config).  1680 blocks x 4096 elems, 4
// independent float4 chains per thread.  X-region XCD-affinity-swizzled
// (panel p -> XCD p/50, matching gemm's reader map).
// Logical regions (4096-elem blocks o): x[0,1600) wq[1600,1616)
//   woff[1616,1625) pad[1625,1632) wkv[1632,1664) wout[1664,1680)
// wf layout (1024x256 bf16): rows[0,256)=Wq [256,400)=Woff [400,512)=0
//   [512,1024)=Wkv
// ---------------------------------------------------------------------------
__global__ __launch_bounds__(256) void cast_all(
    const float* __restrict__ x,   const float* __restrict__ Wq,
    const float* __restrict__ Woff,const float* __restrict__ Wkv,
    const float* __restrict__ Wout,
    ushort* __restrict__ xb, ushort* __restrict__ wf, ushort* __restrict__ woutb)
{
    const int bid = blockIdx.x;
    const int o = (bid < 1600) ? ((bid >> 3) + (bid & 7) * 200) : bid;
    if (o >= 1625 && o < 1632) {   // zero-fill wf rows 400..511
        const int i = (o - 1625) * 4096 + threadIdx.x * 4;
        ushort4 z; z.x = 0; z.y = 0; z.z = 0; z.w = 0;
        #pragma unroll
        for (int k = 0; k < 4; ++k)
            *(ushort4*)(wf + 400 * 256 + i + k * 1024) = z;
        return;
    }
    const float* src; ushort* dst; int base;
    if      (o < 1600) { src = x;    dst = xb;              base = o; }
    else if (o < 1616) { src = Wq;   dst = wf;              base = o - 1600; }
    else if (o < 1625) { src = Woff; dst = wf + 256 * 256;  base = o - 1616; }
    else if (o < 1664) { src = Wkv;  dst = wf + 512 * 256;  base = o - 1632; }
    else               { src = Wout; dst = woutb;           base = o - 1664; }
    const int i0 = base * 4096 + threadIdx.x * 4;
    float4 v[4];
    #pragma unroll
    for (int k = 0; k < 4; ++k) v[k] = *(const float4*)(src + i0 + k * 1024);
    #pragma unroll
    for (int k = 0; k < 4; ++k) {
        ushort4 o4;
        o4.x = f2bf(v[k].x); o4.y = f2bf(v[k].y);
        o4.z = f2bf(v[k].z); o4.w = f2bf(v[k].w);
        *(ushort4*)(dst + i0 + k * 1024) = o4;
    }
}

// ---------------------------------------------------------------------------
// 64x64-tile 2-phase double-buffered GEMM (r6/r7-measured TLP-first: 32 KB
// LDS -> 5 blocks/CU).  stage(t+1) BEFORE compute(t), ONE __syncthreads per
// K-step.  XOR swizzle; XCD map: token-panel p on XCD p/50.
// MODE 0: N=1024 fused epilogue q bf16 | off s16 x4096 | k/v scatter
//   (grid 6400).  MODE 1: N=256 fp32 out-projection (grid 1600).
// ---------------------------------------------------------------------------
template <int MODE>
__global__ __launch_bounds__(256) void gemm64(
    const ushort* __restrict__ Xb,
    const ushort* __restrict__ Wf,
    const float* __restrict__ bq, const float* __restrict__ boff,
    const float* __restrict__ bkv,
    ushort* __restrict__ qb, short* __restrict__ offp,
    ushort* __restrict__ kfb, ushort* __restrict__ vfb,
    float* __restrict__ Yout)
{
    constexpr int NBN = (MODE == 0) ? 16 : 4;  // 64-col n-blocks per m-panel
    __shared__ ushort As[2][64 * 64];          // 2 x 8 KB
    __shared__ ushort Bs[2][64 * 64];          // 2 x 8 KB

    const int tid = threadIdx.x;
    const int bid = blockIdx.x;
    const int xcd = bid & 7;
    const int j   = bid >> 3;
    const int block_n = (j % NBN) * 64;
    const int block_m = (xcd * 50 + j / NBN) * 64;   // 400 m-panels, 50/XCD

    const int wave = tid >> 6, lane = tid & 63;
    const int wr = (wave >> 1) * 32, wc = (wave & 1) * 32;
    const int l15 = lane & 15, quad = lane >> 4;

    const int srow  = lane >> 3;                 // 0..7
    const int sslot = (lane & 7) ^ srow;         // pre-swizzled src slot

    floatx4 acc[2][2];
    #pragma unroll
    for (int i = 0; i < 2; ++i)
        #pragma unroll
        for (int jj = 0; jj < 2; ++jj) {
            acc[i][jj][0] = 0.f; acc[i][jj][1] = 0.f;
            acc[i][jj][2] = 0.f; acc[i][jj][3] = 0.f;
        }

    auto stage = [&](int buf, int kt) {
        #pragma unroll
        for (int i = 0; i < 2; ++i) {
            const int rb = wave * 16 + i * 8;
            const ushort* sa = Xb + (size_t)(block_m + rb + srow) * KDIM + kt + sslot * 8;
            const ushort* sb = Wf + (size_t)(block_n + rb + srow) * KDIM + kt + sslot * 8;
            __builtin_amdgcn_global_load_lds(AS1C(sa), AS3(&As[buf][rb * 64]), 16, 0, 0);
            __builtin_amdgcn_global_load_lds(AS1C(sb), AS3(&Bs[buf][rb * 64]), 16, 0, 0);
        }
    };

    auto compute = [&](int buf) {
        #pragma unroll
        for (int ks2 = 0; ks2 < 2; ++ks2) {
            short8 af[2], bfr[2];
            #pragma unroll
            for (int f = 0; f < 2; ++f) {
                const int ra  = wr + f * 16 + l15;
                const int rbb = wc + f * 16 + l15;
                const int sl  = (((ks2 * 4 + quad) ^ (l15 & 7))) * 8;
                af[f]  = *(const short8*)&As[buf][ra * 64 + sl];
                bfr[f] = *(const short8*)&Bs[buf][rbb * 64 + sl];
            }
            #pragma unroll
            for (int fm = 0; fm < 2; ++fm)
                #pragma unroll
                for (int fn = 0; fn < 2; ++fn)
                    acc[fm][fn] = __builtin_amdgcn_mfma_f32_16x16x32_bf16(
                        af[fm], bfr[fn], acc[fm][fn], 0, 0, 0);
        }
    };

    stage(0, 0);
    __syncthreads();
    #pragma unroll
    for (int t = 0; t < 3; ++t) {
        stage((t + 1) & 1, (t + 1) * 64);
        compute(t & 1);
        __syncthreads();
    }
    compute(1);   // tile 3 in buf 1

    // ---- epilogue: C/D layout col=lane&15, row=quad*4+reg ----
    const int bb  = block_m / NTOK;
    const int nn0 = block_m - bb * NTOK;
    #pragma unroll
    for (int fn = 0; fn < 2; ++fn) {
        const int col = block_n + wc + fn * 16 + l15;
        float bcol;
        if (MODE == 1) {
            bcol = bq[col];
        } else {
            if      (col < 256) bcol = bq[col];
            else if (col < 400) bcol = boff[col - 256];
            else if (col < 512) bcol = 0.f;
            else                bcol = bkv[col - 512];
        }
        #pragma unroll
        for (int fm = 0; fm < 2; ++fm) {
            #pragma unroll
            for (int r = 0; r < 4; ++r) {
                const int rloc = wr + fm * 16 + quad * 4 + r;
                const int row  = block_m + rloc;
                const float val = acc[fm][fn][r] + bcol;
                if (MODE == 1) {
                    Yout[(size_t)row * DMODEL + col] = val;
                } else {
                    if (col < 256) {
                        qb[(size_t)row * DMODEL + col] = f2bf(val);
                    } else if (col < 400) {
                        offp[(size_t)row * 144 + (col - 256)] =
                            (short)__float2int_rn(tanhf(val) * 16384.0f);
                    } else if (col >= 512) {
                        const int c2 = col - 512;
                        const int hh = (c2 & 255) >> 5, cc = c2 & 31;
                        const int nn = nn0 + rloc;
                        const size_t o = (((size_t)(bb * NHEAD + hh)) * NTOK + nn) * HDIM + cc;
                        if (c2 < 256) kfb[o] = f2bf(val);
                        else          vfb[o] = f2bf(val);
                    }
                }
            }
        }
    }
}

// ---------------------------------------------------------------------------
// Deformable sampling + softmax attention (r11 structure) with two VALU cuts:
// 1. OWNER-LANE SETUP + SHFL BROADCAST: idx/wt are identical across the 4
//    lanes sharing a (token,head).  Lane lc computes only points lc*3..lc*3+2
//    (lane 3: harmless dups of p=8); group g's 3 points are all owned by
//    lane lc=g, broadcast via 24 __shfl (DS pipe, idle).  Setup runs 3x
//    instead of 9x per lane.
// 2. INTERIOR FAST PATH: |off|<=4, so tokens with bx in [4,154], by in [4,34]
//    (~73%) skip all clamp/valid logic; corner idx = i00 +32/+5120/+5152.
// Plain-exp softmax, s16 offsets, XCD-affinity remap: unchanged (r7/r9/r11).
// ---------------------------------------------------------------------------
__global__ __launch_bounds__(256, 3) void deform_attn(
    const ushort* __restrict__ qb,    // (M,256) bf16
    const short* __restrict__ offp,   // (M,144) s16 x4096
    const ushort* __restrict__ kfb,   // (B*H,N,32) bf16
    const ushort* __restrict__ vfb,
    ushort* __restrict__ attnb)       // (M,256) bf16
{
    const int lane = threadIdx.x & 63;
    // affinity remap: o = (bid>>3) + (bid&7)*400  (bijective on [0,3200))
    const int o = ((int)blockIdx.x >> 3) + ((int)blockIdx.x & 7) * 400;
    const int token = o * 8 + (threadIdx.x >> 6) * 2 + (lane >> 5);
    const int h = (lane >> 2) & 7, lc = lane & 3;
    const int b = token / NTOK, n = token % NTOK;

    const uint4 qu = *(const uint4*)(qb + (size_t)token * DMODEL + h * HDIM + lc * 8);
    f32x2 q2[4]; unpack8v(qu, q2);
    #pragma unroll
    for (int i = 0; i < 4; ++i) q2[i] *= 0.17677669529663687f;   // 32^-0.5

    const short* ob = offp + (size_t)token * 144 + h * (NPTS * 2);
    const float bx = (float)(n % WSP), by = (float)(n / WSP);
    const ushort* kbase = kfb + (size_t)(b * NHEAD + h) * NTOK * HDIM + lc * 8;
    const ushort* vbase = vfb + (size_t)(b * NHEAD + h) * NTOK * HDIM + lc * 8;

    // ---- owner setup: this lane's 3 points (p = lc*3+i, clamped) ----
    const bool interior = (bx >= 4.0f) & (bx <= 154.0f) & (by >= 4.0f) & (by <= 34.0f);
    int   idxO[3][4];
    float wtO[3][4];
    #pragma unroll
    for (int i = 0; i < 3; ++i) {
        const int p = min(lc * 3 + i, NPTS - 1);
        const int u = *(const int*)(ob + 2 * p);
        const float ofx = (float)((short)(u & 0xFFFF)) * (1.0f / 4096.0f);
        const float ofy = (float)(u >> 16) * (1.0f / 4096.0f);
        const float sx = bx + ofx, sy = by + ofy;
        const float fx0 = floorf(sx), fy0 = floorf(sy);
        const float wx1 = sx - fx0, wx0 = 1.0f - wx1;
        const float wy1 = sy - fy0, wy0 = 1.0f - wy1;
        if (interior) {
            const int i00 = ((int)fy0 * WSP + (int)fx0) * HDIM;
            wtO[i][0] = wx0 * wy0; wtO[i][1] = wx1 * wy0;
            wtO[i][2] = wx0 * wy1; wtO[i][3] = wx1 * wy1;
            idxO[i][0] = i00;
            idxO[i][1] = i00 + HDIM;
            idxO[i][2] = i00 + WSP * HDIM;
            idxO[i][3] = i00 + WSP * HDIM + HDIM;
        } else {
            const int ix0 = (int)fx0, iy0 = (int)fy0;
            const int ix1 = ix0 + 1, iy1 = iy0 + 1;
            const bool vx0 = (ix0 >= 0) & (ix0 <= WSP - 1);
            const bool vx1 = (ix1 >= 0) & (ix1 <= WSP - 1);
            const bool vy0 = (iy0 >= 0) & (iy0 <= HSP - 1);
            const bool vy1 = (iy1 >= 0) & (iy1 <= HSP - 1);
            const int cx0 = min(max(ix0, 0), WSP - 1);
            const int cx1 = min(max(ix1, 0), WSP - 1);
            const int cy0 = min(max(iy0, 0), HSP - 1);
            const int cy1 = min(max(iy1, 0), HSP - 1);
            wtO[i][0] = wx0 * wy0 * (float)(vx0 && vy0);
            wtO[i][1] = wx1 * wy0 * (float)(vx1 && vy0);
            wtO[i][2] = wx0 * wy1 * (float)(vx0 && vy1);
            wtO[i][3] = wx1 * wy1 * (float)(vx1 && vy1);
            idxO[i][0] = (cy0 * WSP + cx0) * HDIM;
            idxO[i][1] = (cy0 * WSP + cx1) * HDIM;
            idxO[i][2] = (cy1 * WSP + cx0) * HDIM;
            idxO[i][3] = (cy1 * WSP + cx1) * HDIM;
        }
    }

    float s = 0.f;
    f32x2 o2[4];
    #pragma unroll
    for (int i = 0; i < 4; ++i) { o2[i].x = 0.f; o2[i].y = 0.f; }

    #pragma unroll
    for (int g = 0; g < 3; ++g) {
        // broadcast group g's idx/wt from owner lane (lc = g)
        const int src = (lane & 60) | g;
        int   idx[3][4];
        float wt[3][4];
        #pragma unroll
        for (int jj = 0; jj < 3; ++jj) {
            #pragma unroll
            for (int c = 0; c < 4; ++c) {
                idx[jj][c] = __shfl(idxO[jj][c], src, 64);
                wt[jj][c]  = __shfl(wtO[jj][c], src, 64);
            }
        }

        // --- K burst (12) then V burst (12): 24 loads in flight ---
        uint4 ku[12], vu[12];
        #pragma unroll
        for (int jj = 0; jj < 3; ++jj)
            #pragma unroll
            for (int c = 0; c < 4; ++c)
                ku[jj * 4 + c] = *(const uint4*)(kbase + idx[jj][c]);
        #pragma unroll
        for (int jj = 0; jj < 3; ++jj)
            #pragma unroll
            for (int c = 0; c < 4; ++c)
                vu[jj * 4 + c] = *(const uint4*)(vbase + idx[jj][c]);

        // --- dots (consume K while V still in flight) ---
        float l[3];
        #pragma unroll
        for (int jj = 0; jj < 3; ++jj) {
            float part = wt[jj][0] * dot8(ku[jj * 4 + 0], q2)
                       + wt[jj][1] * dot8(ku[jj * 4 + 1], q2)
                       + wt[jj][2] * dot8(ku[jj * 4 + 2], q2)
                       + wt[jj][3] * dot8(ku[jj * 4 + 3], q2);
            part += __shfl_xor(part, 1, 64);
            part += __shfl_xor(part, 2, 64);
            l[jj] = part;
        }

        // --- plain-exp softmax accumulation (r7-proven: logits bounded) ---
        const float e0 = __expf(l[0]);
        const float e1 = __expf(l[1]);
        const float e2 = __expf(l[2]);
        s += e0 + e1 + e2;
        const float e[3] = {e0, e1, e2};

        // --- V accumulate ---
        #pragma unroll
        for (int jj = 0; jj < 3; ++jj) {
            #pragma unroll
            for (int c = 0; c < 4; ++c) {
                f32x2 vv[4]; unpack8v(vu[jj * 4 + c], vv);
                const float ew = e[jj] * wt[jj][c];
                #pragma unroll
                for (int i = 0; i < 4; ++i) o2[i] += vv[i] * ew;
            }
        }
    }

    const float inv = 1.0f / s;
    uint4 ru;
    ru.x = (uint)f2bf(o2[0].x * inv) | ((uint)f2bf(o2[0].y * inv) << 16);
    ru.y = (uint)f2bf(o2[1].x * inv) | ((uint)f2bf(o2[1].y * inv) << 16);
    ru.z = (uint)f2bf(o2[2].x * inv) | ((uint)f2bf(o2[2].y * inv) << 16);
    ru.w = (uint)f2bf(o2[3].x * inv) | ((uint)f2bf(o2[3].y * inv) << 16);
    *(uint4*)(attnb + (size_t)token * DMODEL + h * HDIM + lc * 8) = ru;
}

// ---------------------------------------------------------------------------
extern "C" void kernel_launch(void* const* d_in, const int* in_sizes, int n_in,
                              void* d_out, int out_size, void* d_ws, size_t ws_size,
                              hipStream_t stream) {
    const float* x    = (const float*)d_in[0];
    const float* Wq   = (const float*)d_in[1];
    const float* bq   = (const float*)d_in[2];
    const float* Woff = (const float*)d_in[3];
    const float* boff = (const float*)d_in[4];
    const float* Wkv  = (const float*)d_in[5];
    const float* bkv  = (const float*)d_in[6];
    const float* Wout = (const float*)d_in[7];
    const float* bout = (const float*)d_in[8];

    // workspace layout (~61 MB)
    ushort* xb    = (ushort*)d_ws;                         // 6,553,600 us (aliased by attnb)
    ushort* qb    = xb + (size_t)MTOT * DMODEL;            // 6,553,600 us
    short*  offp  = (short*)(qb + (size_t)MTOT * DMODEL);  // 3,686,400 s16
    ushort* kfb   = (ushort*)(offp + (size_t)MTOT * 144);  // 6,553,600 us
    ushort* vfb   = kfb + (size_t)MTOT * DMODEL;           // 6,553,600 us
    ushort* wf    = vfb + (size_t)MTOT * DMODEL;           // 262,144 us (1024x256)
    ushort* woutb = wf + 262144;                           // 65,536 us
    ushort* attnb = xb;   // xb dead after gemm64<0>

    cast_all<<<dim3(1680), dim3(256), 0, stream>>>(x, Wq, Woff, Wkv, Wout,
                                                   xb, wf, woutb);

    gemm64<0><<<dim3(6400), dim3(256), 0, stream>>>(xb, wf, bq, boff, bkv,
                                                    qb, offp, kfb, vfb, nullptr);

    deform_attn<<<dim3(3200), dim3(256), 0, stream>>>(qb, offp, kfb, vfb, attnb);

    gemm64<1><<<dim3(1600), dim3(256), 0, stream>>>(attnb, woutb, bout,
                                                    nullptr, nullptr, nullptr,
                                                    nullptr, nullptr, nullptr,
                                                    (float*)d_out);
}

// Round 13
// 179.630 us; speedup vs baseline: 1.1535x; 1.0476x over previous
//
#include <hip/hip_runtime.h>
#include <math.h>

#define BSZ    4
#define NTOK   6400      // 40*160
#define DMODEL 256
#define NHEAD  8
#define HDIM   32
#define NPTS   9
#define HSP    40
#define WSP    160
#define KDIM   256
#define MTOT   (BSZ*NTOK)   // 25600

typedef short  short8  __attribute__((ext_vector_type(8)));
typedef float  floatx4 __attribute__((ext_vector_type(4)));
typedef float  f32x2   __attribute__((ext_vector_type(2)));

__device__ __forceinline__ ushort f2bf(float f) {
    uint u = __float_as_uint(f);
    u = (u + 0x7FFFu + ((u >> 16) & 1u)) >> 16;   // RNE
    return (ushort)u;
}

// unpack 8 packed bf16 (uint4) -> 4 x f32x2 (pairs, channel order preserved)
__device__ __forceinline__ void unpack8v(uint4 u, f32x2* f) {
    f[0].x = __uint_as_float(u.x << 16); f[0].y = __uint_as_float(u.x & 0xFFFF0000u);
    f[1].x = __uint_as_float(u.y << 16); f[1].y = __uint_as_float(u.y & 0xFFFF0000u);
    f[2].x = __uint_as_float(u.z << 16); f[2].y = __uint_as_float(u.z & 0xFFFF0000u);
    f[3].x = __uint_as_float(u.w << 16); f[3].y = __uint_as_float(u.w & 0xFFFF0000u);
}

// dot of 8 bf16 (packed in uint4) with q2[4] (f32x2 pairs) -> scalar
__device__ __forceinline__ float dot8(uint4 u, const f32x2* q2) {
    f32x2 a; a.x = 0.f; a.y = 0.f;
    f32x2 t;
    t.x = __uint_as_float(u.x << 16); t.y = __uint_as_float(u.x & 0xFFFF0000u);
    a += t * q2[0];
    t.x = __uint_as_float(u.y << 16); t.y = __uint_as_float(u.y & 0xFFFF0000u);
    a += t * q2[1];
    t.x = __uint_as_float(u.z << 16); t.y = __uint_as_float(u.z & 0xFFFF0000u);
    a += t * q2[2];
    t.x = __uint_as_float(u.w << 16); t.y = __uint_as_float(u.w & 0xFFFF0000u);
    a += t * q2[3];
    return a.x + a.y;
}

#define AS1C(p) ((const __attribute__((address_space(1))) void*)(p))
#define AS3(p)  ((__attribute__((address_space(3))) void*)(p))

// ---------------------------------------------------------------------------
// All fp32->bf16 casts (r7-measured config).  1680 blocks x 4096 elems, 4
// independent float4 chains per thread.  X-region XCD-affinity-swizzled
// (panel p -> XCD p/50, matching gemm's reader map).
// Logical regions (4096-elem blocks o): x[0,1600) wq[1600,1616)
//   woff[1616,1625) pad[1625,1632) wkv[1632,1664) wout[1664,1680)
// wf layout (1024x256 bf16): rows[0,256)=Wq [256,400)=Woff [400,512)=0
//   [512,1024)=Wkv
// ---------------------------------------------------------------------------
__global__ __launch_bounds__(256) void cast_all(
    const float* __restrict__ x,   const float* __restrict__ Wq,
    const float* __restrict__ Woff,const float* __restrict__ Wkv,
    const float* __restrict__ Wout,
    ushort* __restrict__ xb, ushort* __restrict__ wf, ushort* __restrict__ woutb)
{
    const int bid = blockIdx.x;
    const int o = (bid < 1600) ? ((bid >> 3) + (bid & 7) * 200) : bid;
    if (o >= 1625 && o < 1632) {   // zero-fill wf rows 400..511
        const int i = (o - 1625) * 4096 + threadIdx.x * 4;
        ushort4 z; z.x = 0; z.y = 0; z.z = 0; z.w = 0;
        #pragma unroll
        for (int k = 0; k < 4; ++k)
            *(ushort4*)(wf + 400 * 256 + i + k * 1024) = z;
        return;
    }
    const float* src; ushort* dst; int base;
    if      (o < 1600) { src = x;    dst = xb;              base = o; }
    else if (o < 1616) { src = Wq;   dst = wf;              base = o - 1600; }
    else if (o < 1625) { src = Woff; dst = wf + 256 * 256;  base = o - 1616; }
    else if (o < 1664) { src = Wkv;  dst = wf + 512 * 256;  base = o - 1632; }
    else               { src = Wout; dst = woutb;           base = o - 1664; }
    const int i0 = base * 4096 + threadIdx.x * 4;
    float4 v[4];
    #pragma unroll
    for (int k = 0; k < 4; ++k) v[k] = *(const float4*)(src + i0 + k * 1024);
    #pragma unroll
    for (int k = 0; k < 4; ++k) {
        ushort4 o4;
        o4.x = f2bf(v[k].x); o4.y = f2bf(v[k].y);
        o4.z = f2bf(v[k].z); o4.w = f2bf(v[k].w);
        *(ushort4*)(dst + i0 + k * 1024) = o4;
    }
}

// ---------------------------------------------------------------------------
// 64x64-tile 2-phase double-buffered GEMM (r6/r7-measured TLP-first: 32 KB
// LDS -> 5 blocks/CU).  stage(t+1) BEFORE compute(t), ONE __syncthreads per
// K-step.  XOR swizzle; XCD map: token-panel p on XCD p/50.
//
// MODE 0 (grid 6000): N=960 useful cols; the all-discard n-block (448..511)
//   is removed from the grid (15 n-blocks/panel, skip jn==7).
//   q/kv epilogue is LDS-STAGED: C tile -> As[0] (dead after K-loop) with
//   col ^ ((row>>2&3)<<4) swizzle (2-way write banks = free), barrier, then
//   2x {ds_read_b128 + global_store_dwordx4} per thread -> fully-coalesced
//   16B stores (r12's 2-byte scatters = half-utilized 64B txns on 38 MB).
//   off region (s16) keeps the scalar path.
// MODE 1 (grid 1600): N=256 fp32 out-projection (64B-coalesced already).
// ---------------------------------------------------------------------------
template <int MODE>
__global__ __launch_bounds__(256) void gemm64(
    const ushort* __restrict__ Xb,
    const ushort* __restrict__ Wf,
    const float* __restrict__ bq, const float* __restrict__ boff,
    const float* __restrict__ bkv,
    ushort* __restrict__ qb, short* __restrict__ offp,
    ushort* __restrict__ kfb, ushort* __restrict__ vfb,
    float* __restrict__ Yout)
{
    __shared__ __align__(16) ushort As[2][64 * 64];   // 2 x 8 KB
    __shared__ __align__(16) ushort Bs[2][64 * 64];   // 2 x 8 KB

    const int tid = threadIdx.x;
    const int bid = blockIdx.x;
    const int xcd = bid & 7;
    const int j   = bid >> 3;
    int block_n, block_m;
    if (MODE == 0) {
        int jn = j % 15; if (jn >= 7) ++jn;           // skip all-discard block
        block_n = jn * 64;
        block_m = (xcd * 50 + j / 15) * 64;           // 400 m-panels, 50/XCD
    } else {
        block_n = (j % 4) * 64;
        block_m = (xcd * 50 + j / 4) * 64;
    }

    const int wave = tid >> 6, lane = tid & 63;
    const int wr = (wave >> 1) * 32, wc = (wave & 1) * 32;
    const int l15 = lane & 15, quad = lane >> 4;

    const int srow  = lane >> 3;                 // 0..7
    const int sslot = (lane & 7) ^ srow;         // pre-swizzled src slot

    floatx4 acc[2][2];
    #pragma unroll
    for (int i = 0; i < 2; ++i)
        #pragma unroll
        for (int jj = 0; jj < 2; ++jj) {
            acc[i][jj][0] = 0.f; acc[i][jj][1] = 0.f;
            acc[i][jj][2] = 0.f; acc[i][jj][3] = 0.f;
        }

    auto stage = [&](int buf, int kt) {
        #pragma unroll
        for (int i = 0; i < 2; ++i) {
            const int rb = wave * 16 + i * 8;
            const ushort* sa = Xb + (size_t)(block_m + rb + srow) * KDIM + kt + sslot * 8;
            const ushort* sb = Wf + (size_t)(block_n + rb + srow) * KDIM + kt + sslot * 8;
            __builtin_amdgcn_global_load_lds(AS1C(sa), AS3(&As[buf][rb * 64]), 16, 0, 0);
            __builtin_amdgcn_global_load_lds(AS1C(sb), AS3(&Bs[buf][rb * 64]), 16, 0, 0);
        }
    };

    auto compute = [&](int buf) {
        #pragma unroll
        for (int ks2 = 0; ks2 < 2; ++ks2) {
            short8 af[2], bfr[2];
            #pragma unroll
            for (int f = 0; f < 2; ++f) {
                const int ra  = wr + f * 16 + l15;
                const int rbb = wc + f * 16 + l15;
                const int sl  = (((ks2 * 4 + quad) ^ (l15 & 7))) * 8;
                af[f]  = *(const short8*)&As[buf][ra * 64 + sl];
                bfr[f] = *(const short8*)&Bs[buf][rbb * 64 + sl];
            }
            #pragma unroll
            for (int fm = 0; fm < 2; ++fm)
                #pragma unroll
                for (int fn = 0; fn < 2; ++fn)
                    acc[fm][fn] = __builtin_amdgcn_mfma_f32_16x16x32_bf16(
                        af[fm], bfr[fn], acc[fm][fn], 0, 0, 0);
        }
    };

    stage(0, 0);
    __syncthreads();
    #pragma unroll
    for (int t = 0; t < 3; ++t) {
        stage((t + 1) & 1, (t + 1) * 64);
        compute(t & 1);
        __syncthreads();
    }
    compute(1);   // tile 3 in buf 1

    // ---- epilogue: C/D layout col=lane&15, row=quad*4+reg ----
    const int bb  = block_m / NTOK;
    const int nn0 = block_m - bb * NTOK;

    if (MODE == 0 && (block_n < 256 || block_n >= 512)) {
        // ---- LDS-staged coalesced store path (q and kv regions) ----
        ushort* Cs = &As[0][0];    // 8 KB, dead after K-loop (last read t=2)
        #pragma unroll
        for (int fn = 0; fn < 2; ++fn) {
            const int col = block_n + wc + fn * 16 + l15;
            const float bcol = (block_n < 256) ? bq[col] : bkv[col - 512];
            #pragma unroll
            for (int fm = 0; fm < 2; ++fm) {
                #pragma unroll
                for (int r = 0; r < 4; ++r) {
                    const int lrow  = wr + fm * 16 + quad * 4 + r;
                    const int lcol  = wc + fn * 16 + l15;
                    const int lcolS = lcol ^ (((lrow >> 2) & 3) << 4);
                    Cs[lrow * 64 + lcolS] = f2bf(acc[fm][fn][r] + bcol);
                }
            }
        }
        __syncthreads();
        #pragma unroll
        for (int p = 0; p < 2; ++p) {
            const int s    = p * 256 + tid;        // 512 16B-segments
            const int lrow = s >> 3;
            const int seg8 = s & 7;
            const int q4   = (lrow >> 2) & 3;
            const int c0p  = (seg8 & 1) * 8 + (((seg8 >> 1) ^ q4) << 4);
            const uint4 v = *(const uint4*)&Cs[lrow * 64 + c0p];
            if (block_n < 256) {
                *(uint4*)&qb[(size_t)(block_m + lrow) * DMODEL + block_n + seg8 * 8] = v;
            } else {
                const int c2 = block_n - 512 + seg8 * 8;
                const int hh = (c2 & 255) >> 5, cc = c2 & 31;
                const int nn = nn0 + lrow;
                const size_t dsto = (((size_t)(bb * NHEAD + hh)) * NTOK + nn) * HDIM + cc;
                if (c2 < 256) *(uint4*)&kfb[dsto] = v;
                else          *(uint4*)&vfb[dsto] = v;
            }
        }
    } else {
        // ---- scalar path: MODE 1 (fp32, 64B-coalesced) and off region ----
        #pragma unroll
        for (int fn = 0; fn < 2; ++fn) {
            const int col = block_n + wc + fn * 16 + l15;
            float bcol;
            if (MODE == 1) {
                bcol = bq[col];
            } else {
                if      (col < 400) bcol = boff[col - 256];
                else                bcol = 0.f;
            }
            #pragma unroll
            for (int fm = 0; fm < 2; ++fm) {
                #pragma unroll
                for (int r = 0; r < 4; ++r) {
                    const int rloc = wr + fm * 16 + quad * 4 + r;
                    const int row  = block_m + rloc;
                    const float val = acc[fm][fn][r] + bcol;
                    if (MODE == 1) {
                        Yout[(size_t)row * DMODEL + col] = val;
                    } else if (col >= 256 && col < 400) {
                        offp[(size_t)row * 144 + (col - 256)] =
                            (short)__float2int_rn(tanhf(val) * 16384.0f);
                    }
                }
            }
        }
    }
}

// ---------------------------------------------------------------------------
// Deformable sampling + softmax attention (r12 structure, unchanged):
// owner-lane setup + shfl broadcast, interior fast path, K/V bursts,
// plain-exp softmax, s16 offsets, XCD-affinity remap.
// ---------------------------------------------------------------------------
__global__ __launch_bounds__(256, 3) void deform_attn(
    const ushort* __restrict__ qb,    // (M,256) bf16
    const short* __restrict__ offp,   // (M,144) s16 x4096
    const ushort* __restrict__ kfb,   // (B*H,N,32) bf16
    const ushort* __restrict__ vfb,
    ushort* __restrict__ attnb)       // (M,256) bf16
{
    const int lane = threadIdx.x & 63;
    // affinity remap: o = (bid>>3) + (bid&7)*400  (bijective on [0,3200))
    const int o = ((int)blockIdx.x >> 3) + ((int)blockIdx.x & 7) * 400;
    const int token = o * 8 + (threadIdx.x >> 6) * 2 + (lane >> 5);
    const int h = (lane >> 2) & 7, lc = lane & 3;
    const int b = token / NTOK, n = token % NTOK;

    const uint4 qu = *(const uint4*)(qb + (size_t)token * DMODEL + h * HDIM + lc * 8);
    f32x2 q2[4]; unpack8v(qu, q2);
    #pragma unroll
    for (int i = 0; i < 4; ++i) q2[i] *= 0.17677669529663687f;   // 32^-0.5

    const short* ob = offp + (size_t)token * 144 + h * (NPTS * 2);
    const float bx = (float)(n % WSP), by = (float)(n / WSP);
    const ushort* kbase = kfb + (size_t)(b * NHEAD + h) * NTOK * HDIM + lc * 8;
    const ushort* vbase = vfb + (size_t)(b * NHEAD + h) * NTOK * HDIM + lc * 8;

    // ---- owner setup: this lane's 3 points (p = lc*3+i, clamped) ----
    const bool interior = (bx >= 4.0f) & (bx <= 154.0f) & (by >= 4.0f) & (by <= 34.0f);
    int   idxO[3][4];
    float wtO[3][4];
    #pragma unroll
    for (int i = 0; i < 3; ++i) {
        const int p = min(lc * 3 + i, NPTS - 1);
        const int u = *(const int*)(ob + 2 * p);
        const float ofx = (float)((short)(u & 0xFFFF)) * (1.0f / 4096.0f);
        const float ofy = (float)(u >> 16) * (1.0f / 4096.0f);
        const float sx = bx + ofx, sy = by + ofy;
        const float fx0 = floorf(sx), fy0 = floorf(sy);
        const float wx1 = sx - fx0, wx0 = 1.0f - wx1;
        const float wy1 = sy - fy0, wy0 = 1.0f - wy1;
        if (interior) {
            const int i00 = ((int)fy0 * WSP + (int)fx0) * HDIM;
            wtO[i][0] = wx0 * wy0; wtO[i][1] = wx1 * wy0;
            wtO[i][2] = wx0 * wy1; wtO[i][3] = wx1 * wy1;
            idxO[i][0] = i00;
            idxO[i][1] = i00 + HDIM;
            idxO[i][2] = i00 + WSP * HDIM;
            idxO[i][3] = i00 + WSP * HDIM + HDIM;
        } else {
            const int ix0 = (int)fx0, iy0 = (int)fy0;
            const int ix1 = ix0 + 1, iy1 = iy0 + 1;
            const bool vx0 = (ix0 >= 0) & (ix0 <= WSP - 1);
            const bool vx1 = (ix1 >= 0) & (ix1 <= WSP - 1);
            const bool vy0 = (iy0 >= 0) & (iy0 <= HSP - 1);
            const bool vy1 = (iy1 >= 0) & (iy1 <= HSP - 1);
            const int cx0 = min(max(ix0, 0), WSP - 1);
            const int cx1 = min(max(ix1, 0), WSP - 1);
            const int cy0 = min(max(iy0, 0), HSP - 1);
            const int cy1 = min(max(iy1, 0), HSP - 1);
            wtO[i][0] = wx0 * wy0 * (float)(vx0 && vy0);
            wtO[i][1] = wx1 * wy0 * (float)(vx1 && vy0);
            wtO[i][2] = wx0 * wy1 * (float)(vx0 && vy1);
            wtO[i][3] = wx1 * wy1 * (float)(vx1 && vy1);
            idxO[i][0] = (cy0 * WSP + cx0) * HDIM;
            idxO[i][1] = (cy0 * WSP + cx1) * HDIM;
            idxO[i][2] = (cy1 * WSP + cx0) * HDIM;
            idxO[i][3] = (cy1 * WSP + cx1) * HDIM;
        }
    }

    float s = 0.f;
    f32x2 o2[4];
    #pragma unroll
    for (int i = 0; i < 4; ++i) { o2[i].x = 0.f; o2[i].y = 0.f; }

    #pragma unroll
    for (int g = 0; g < 3; ++g) {
        // broadcast group g's idx/wt from owner lane (lc = g)
        const int src = (lane & 60) | g;
        int   idx[3][4];
        float wt[3][4];
        #pragma unroll
        for (int jj = 0; jj < 3; ++jj) {
            #pragma unroll
            for (int c = 0; c < 4; ++c) {
                idx[jj][c] = __shfl(idxO[jj][c], src, 64);
                wt[jj][c]  = __shfl(wtO[jj][c], src, 64);
            }
        }

        // --- K burst (12) then V burst (12): 24 loads in flight ---
        uint4 ku[12], vu[12];
        #pragma unroll
        for (int jj = 0; jj < 3; ++jj)
            #pragma unroll
            for (int c = 0; c < 4; ++c)
                ku[jj * 4 + c] = *(const uint4*)(kbase + idx[jj][c]);
        #pragma unroll
        for (int jj = 0; jj < 3; ++jj)
            #pragma unroll
            for (int c = 0; c < 4; ++c)
                vu[jj * 4 + c] = *(const uint4*)(vbase + idx[jj][c]);

        // --- dots (consume K while V still in flight) ---
        float l[3];
        #pragma unroll
        for (int jj = 0; jj < 3; ++jj) {
            float part = wt[jj][0] * dot8(ku[jj * 4 + 0], q2)
                       + wt[jj][1] * dot8(ku[jj * 4 + 1], q2)
                       + wt[jj][2] * dot8(ku[jj * 4 + 2], q2)
                       + wt[jj][3] * dot8(ku[jj * 4 + 3], q2);
            part += __shfl_xor(part, 1, 64);
            part += __shfl_xor(part, 2, 64);
            l[jj] = part;
        }

        // --- plain-exp softmax accumulation (r7-proven: logits bounded) ---
        const float e0 = __expf(l[0]);
        const float e1 = __expf(l[1]);
        const float e2 = __expf(l[2]);
        s += e0 + e1 + e2;
        const float e[3] = {e0, e1, e2};

        // --- V accumulate ---
        #pragma unroll
        for (int jj = 0; jj < 3; ++jj) {
            #pragma unroll
            for (int c = 0; c < 4; ++c) {
                f32x2 vv[4]; unpack8v(vu[jj * 4 + c], vv);
                const float ew = e[jj] * wt[jj][c];
                #pragma unroll
                for (int i = 0; i < 4; ++i) o2[i] += vv[i] * ew;
            }
        }
    }

    const float inv = 1.0f / s;
    uint4 ru;
    ru.x = (uint)f2bf(o2[0].x * inv) | ((uint)f2bf(o2[0].y * inv) << 16);
    ru.y = (uint)f2bf(o2[1].x * inv) | ((uint)f2bf(o2[1].y * inv) << 16);
    ru.z = (uint)f2bf(o2[2].x * inv) | ((uint)f2bf(o2[2].y * inv) << 16);
    ru.w = (uint)f2bf(o2[3].x * inv) | ((uint)f2bf(o2[3].y * inv) << 16);
    *(uint4*)(attnb + (size_t)token * DMODEL + h * HDIM + lc * 8) = ru;
}

// ---------------------------------------------------------------------------
extern "C" void kernel_launch(void* const* d_in, const int* in_sizes, int n_in,
                              void* d_out, int out_size, void* d_ws, size_t ws_size,
                              hipStream_t stream) {
    const float* x    = (const float*)d_in[0];
    const float* Wq   = (const float*)d_in[1];
    const float* bq   = (const float*)d_in[2];
    const float* Woff = (const float*)d_in[3];
    const float* boff = (const float*)d_in[4];
    const float* Wkv  = (const float*)d_in[5];
    const float* bkv  = (const float*)d_in[6];
    const float* Wout = (const float*)d_in[7];
    const float* bout = (const float*)d_in[8];

    // workspace layout (~61 MB)
    ushort* xb    = (ushort*)d_ws;                         // 6,553,600 us (aliased by attnb)
    ushort* qb    = xb + (size_t)MTOT * DMODEL;            // 6,553,600 us
    short*  offp  = (short*)(qb + (size_t)MTOT * DMODEL);  // 3,686,400 s16
    ushort* kfb   = (ushort*)(offp + (size_t)MTOT * 144);  // 6,553,600 us
    ushort* vfb   = kfb + (size_t)MTOT * DMODEL;           // 6,553,600 us
    ushort* wf    = vfb + (size_t)MTOT * DMODEL;           // 262,144 us (1024x256)
    ushort* woutb = wf + 262144;                           // 65,536 us
    ushort* attnb = xb;   // xb dead after gemm64<0>

    cast_all<<<dim3(1680), dim3(256), 0, stream>>>(x, Wq, Woff, Wkv, Wout,
                                                   xb, wf, woutb);

    gemm64<0><<<dim3(6000), dim3(256), 0, stream>>>(xb, wf, bq, boff, bkv,
                                                    qb, offp, kfb, vfb, nullptr);

    deform_attn<<<dim3(3200), dim3(256), 0, stream>>>(qb, offp, kfb, vfb, attnb);

    gemm64<1><<<dim3(1600), dim3(256), 0, stream>>>(attnb, woutb, bout,
                                                    nullptr, nullptr, nullptr,
                                                    nullptr, nullptr, nullptr,
                                                    (float*)d_out);
}